// Round 13
// baseline (344.058 us; speedup 1.0000x reference)
//
#include <hip/hip_runtime.h>
#include <hip/hip_bf16.h>
#include <hip/hip_cooperative_groups.h>

namespace cg = cooperative_groups;

typedef __attribute__((ext_vector_type(8))) short bf16x8;
typedef __attribute__((ext_vector_type(4))) float f32x4;
typedef unsigned short u16;
typedef unsigned int u32;

#define NH 8
#define NN 4096
#define MM 4096
#define KST 40                  // K LDS row stride in u16 (80 B, 16B-aligned)
#define VST 72                  // V LDS row stride in u16 (144 B, 16B-aligned)
#define VSZ (32 * VST)          // one 64-key V sub-tile
#define SMEM_BYTES 19456        // max over phases (flash: 10240 + 9216)

__device__ __forceinline__ u16 f2bf(float f) {
  u32 b = __float_as_uint(f);
  b += 0x7FFFu + ((b >> 16) & 1u);   // RNE to bf16
  return (u16)(b >> 16);
}

__device__ __forceinline__ u32 pack_rnu(float a, float b) {
  u32 ua = __float_as_uint(a) + 0x8000u;
  u32 ub = __float_as_uint(b) + 0x8000u;
#if __has_builtin(__builtin_amdgcn_perm)
  return __builtin_amdgcn_perm(ub, ua, 0x07060302u);  // {ua.b2,ua.b3,ub.b2,ub.b3}
#else
  return (ua >> 16) | (ub & 0xFFFF0000u);
#endif
}

#if __has_builtin(__builtin_amdgcn_exp2f)
__device__ __forceinline__ float exp2_fast(float x) { return __builtin_amdgcn_exp2f(x); }
#else
__device__ __forceinline__ float exp2_fast(float x) { return __expf(x * 0.69314718055994531f); }
#endif

// ---------------- device bodies shared by fused + fallback ----------------

__device__ __forceinline__ void proj_body(
    int bid, int tid, void* smem,
    const float* __restrict__ x, const float* __restrict__ y,
    const float* __restrict__ Wq, const float* __restrict__ bq,
    const float* __restrict__ Wk, const float* __restrict__ bk,
    const float* __restrict__ Wv, const float* __restrict__ bv,
    u16* __restrict__ qs, u16* __restrict__ ks, u16* __restrict__ vT)
{
  if (bid < 256) {
    // ---- q/k path ----
    int idx = bid * 256 + tid;                  // 65536 total
    int t = idx >> 15;                          // 0 = q (from x), 1 = k (from y)
    int h = (idx >> 12) & 7;
    int row = idx & 4095;
    const float* src = (t ? y : x) + row * 16;
    const float* W = (t ? Wk : Wq) + (h << 9);
    const float* b = (t ? bk : bq) + (h << 5);
    const float scale = t ? 1.0f : 0.25503635116465163f;  // (1/sqrt32)*log2e in q
    float4 r4[4];
#pragma unroll
    for (int i = 0; i < 4; ++i) r4[i] = ((const float4*)src)[i];
    const float* r = (const float*)r4;
    u16* out = (t ? ks : qs) + (idx & 32767) * 32;      // (h*4096+row)*32
#pragma unroll
    for (int j = 0; j < 32; ++j) {
      float a = b[j];
#pragma unroll
      for (int i = 0; i < 16; ++i) a = fmaf(r[i], W[i * 32 + j], a);
      out[j] = f2bf(a * scale);
    }
  } else {
    // ---- v path: transposed + key-permuted within each 32-key chunk ----
    u16 (*sv)[33] = (u16(*)[33])smem;
    int vb = bid - 256;
    int h = vb >> 4;
    int kb = (vb & 15) << 8;           // 256 keys per block
    const float* src = y + (kb + tid) * 16;
    const float* W = Wv + (h << 9);
    const float* b = bv + (h << 5);
    float4 r4[4];
#pragma unroll
    for (int i = 0; i < 4; ++i) r4[i] = ((const float4*)src)[i];
    const float* r = (const float*)r4;
#pragma unroll
    for (int j = 0; j < 32; ++j) {
      float a = b[j];
#pragma unroll
      for (int i = 0; i < 16; ++i) a = fmaf(r[i], W[i * 32 + j], a);
      sv[tid][j] = f2bf(a);
    }
    __syncthreads();
    int dv = tid >> 3;
    int c = (tid & 7) << 5;            // 32-key chunk
    u16* dst = vT + (((h << 5) + dv) << 12) + kb + c;
#pragma unroll
    for (int q = 0; q < 4; ++q) {      // positions 8q..8q+7 <- keys {4q+r, 16+4q+r}
      uint4 w;
      w.x = (u32)sv[c + 4 * q + 0][dv]      | ((u32)sv[c + 4 * q + 1][dv] << 16);
      w.y = (u32)sv[c + 4 * q + 2][dv]      | ((u32)sv[c + 4 * q + 3][dv] << 16);
      w.z = (u32)sv[c + 16 + 4 * q + 0][dv] | ((u32)sv[c + 16 + 4 * q + 1][dv] << 16);
      w.w = (u32)sv[c + 16 + 4 * q + 2][dv] | ((u32)sv[c + 16 + 4 * q + 3][dv] << 16);
      *(uint4*)(dst + q * 8) = w;
    }
  }
}

// r7-exact flash body. bid -> (qt, h, z) via r7's dim3(32, NH, S) linearization.
__device__ __forceinline__ void flash_body(
    int bid, int tid, void* smem,
    const u16* __restrict__ qs, const u16* __restrict__ ksrc,
    const u16* __restrict__ vT, float* __restrict__ accP,
    float* __restrict__ lsumP)
{
  u16* sK = (u16*)smem;            // 128 keys x 32 dq  (10240 B)
  u16* sVT = sK + 128 * KST;       // 2 sub x 32 dv x 64 keys (9216 B)
  const int qt = bid & 31;
  const int h = (bid >> 5) & 7;
  const int z = bid >> 8;          // 4 key-splits
  const int nIter = 8;             // stages of 128 keys (1024 keys/split)
  const int kb0 = z << 10;
  const int wv = tid >> 6;
  const int lane = tid & 63;
  const int d = lane & 15;         // qrow-in-16 / A-row index / C col
  const int g = lane >> 4;         // lane group
  const int qrowA = (qt << 7) + (wv << 5) + d;   // wave owns rows [wv*32, wv*32+32)
  const int qrowB = qrowA + 16;

  union U4 { uint4 q; bf16x8 v; };
  U4 qfA, qfB;                     // slot (g,j) -> k = 8g+j (same map on K side)
  qfA.q = *(const uint4*)(qs + (((h << 12) + qrowA) << 5) + (g << 3));
  qfB.q = *(const uint4*)(qs + (((h << 12) + qrowB) << 5) + (g << 3));

  float lsA = 0.f, lsB = 0.f;
  f32x4 accA0 = {0.f, 0.f, 0.f, 0.f}, accA1 = {0.f, 0.f, 0.f, 0.f};
  f32x4 accB0 = {0.f, 0.f, 0.f, 0.f}, accB1 = {0.f, 0.f, 0.f, 0.f};
  const f32x4 zero = {0.f, 0.f, 0.f, 0.f};

  const u16* gK = ksrc + (h << 17) + (kb0 << 5) + ((tid >> 1) << 5) + ((tid & 1) << 4);
  const u16* gV = vT + (((h << 5) + (tid >> 3)) << 12) + kb0 + ((tid & 7) << 4);
  u16* wK = sK + (tid >> 1) * KST + ((tid & 1) << 4);
  u16* wV = sVT + ((tid & 7) >> 2) * VSZ + (tid >> 3) * VST + ((tid & 7) & 3) * 16;

  {
    uint4 a = *(const uint4*)gK, b = *(const uint4*)(gK + 8);
    uint4 c = *(const uint4*)gV, e = *(const uint4*)(gV + 8);
    *(uint4*)wK = a; *(uint4*)(wK + 8) = b;
    *(uint4*)wV = c; *(uint4*)(wV + 8) = e;
  }
  __syncthreads();

  auto compute = [&](const u16* kb, const u16* vb) {
    U4 kf0, kf1, kf2, kf3;          // K frags: keys 16t+d, k = 8g+j contiguous
    kf0.q = *(const uint4*)(kb + (0 * 16 + d) * KST + (g << 3));
    kf1.q = *(const uint4*)(kb + (1 * 16 + d) * KST + (g << 3));
    kf2.q = *(const uint4*)(kb + (2 * 16 + d) * KST + (g << 3));
    kf3.q = *(const uint4*)(kb + (3 * 16 + d) * KST + (g << 3));
    U4 vf0, vf1, vf2, vf3;          // V frags (vT key-permuted: group-g block at 8g)
    {
      const u16* vp = vb + d * VST;
      vf0.q = *(const uint4*)(vp + (g << 3));
      vf1.q = *(const uint4*)(vp + 32 + (g << 3));
      vp += 16 * VST;
      vf2.q = *(const uint4*)(vp + (g << 3));
      vf3.q = *(const uint4*)(vp + 32 + (g << 3));
    }
#define QTILE(QF, ACC0, ACC1, LS)                                              \
    {                                                                          \
      f32x4 s0, s1, s2, s3;                                                    \
      s0 = __builtin_amdgcn_mfma_f32_16x16x32_bf16(kf0.v, QF.v, zero, 0, 0, 0);\
      s1 = __builtin_amdgcn_mfma_f32_16x16x32_bf16(kf1.v, QF.v, zero, 0, 0, 0);\
      s2 = __builtin_amdgcn_mfma_f32_16x16x32_bf16(kf2.v, QF.v, zero, 0, 0, 0);\
      s3 = __builtin_amdgcn_mfma_f32_16x16x32_bf16(kf3.v, QF.v, zero, 0, 0, 0);\
      float e0 = exp2_fast(s0.x), e1 = exp2_fast(s0.y);                        \
      float e2 = exp2_fast(s0.z), e3 = exp2_fast(s0.w);                        \
      float e4 = exp2_fast(s1.x), e5 = exp2_fast(s1.y);                        \
      float e6 = exp2_fast(s1.z), e7 = exp2_fast(s1.w);                        \
      float e8 = exp2_fast(s2.x), e9 = exp2_fast(s2.y);                        \
      float e10 = exp2_fast(s2.z), e11 = exp2_fast(s2.w);                      \
      float e12 = exp2_fast(s3.x), e13 = exp2_fast(s3.y);                      \
      float e14 = exp2_fast(s3.z), e15 = exp2_fast(s3.w);                      \
      LS += (((e0 + e1) + (e2 + e3)) + ((e4 + e5) + (e6 + e7)))                \
          + (((e8 + e9) + (e10 + e11)) + ((e12 + e13) + (e14 + e15)));         \
      union { u32 w[4]; bf16x8 v; } pb0, pb1;                                  \
      pb0.w[0] = pack_rnu(e0, e1);   pb0.w[1] = pack_rnu(e2, e3);              \
      pb0.w[2] = pack_rnu(e4, e5);   pb0.w[3] = pack_rnu(e6, e7);              \
      pb1.w[0] = pack_rnu(e8, e9);   pb1.w[1] = pack_rnu(e10, e11);            \
      pb1.w[2] = pack_rnu(e12, e13); pb1.w[3] = pack_rnu(e14, e15);            \
      ACC0 = __builtin_amdgcn_mfma_f32_16x16x32_bf16(vf0.v, pb0.v, ACC0, 0, 0, 0); \
      ACC0 = __builtin_amdgcn_mfma_f32_16x16x32_bf16(vf1.v, pb1.v, ACC0, 0, 0, 0); \
      ACC1 = __builtin_amdgcn_mfma_f32_16x16x32_bf16(vf2.v, pb0.v, ACC1, 0, 0, 0); \
      ACC1 = __builtin_amdgcn_mfma_f32_16x16x32_bf16(vf3.v, pb1.v, ACC1, 0, 0, 0); \
    }
    QTILE(qfA, accA0, accA1, lsA)
    QTILE(qfB, accB0, accB1, lsB)
#undef QTILE
  };

#pragma unroll 1
  for (int it = 0; it < nIter; ++it) {
    uint4 a, b, c, e;
    if (it < nIter - 1) {            // prefetch next 128 keys into registers
      gK += 4096; gV += 128;
      a = *(const uint4*)gK; b = *(const uint4*)(gK + 8);
      c = *(const uint4*)gV; e = *(const uint4*)(gV + 8);
    }
    compute(sK, sVT);
    compute(sK + 64 * KST, sVT + VSZ);
    __syncthreads();               // all reads of current stage done
    if (it < nIter - 1) {
      *(uint4*)wK = a; *(uint4*)(wK + 8) = b;   // vmcnt drained under compute
      *(uint4*)wV = c; *(uint4*)(wV + 8) = e;
      __syncthreads();             // stage visible
    }
  }

  lsA += __shfl_xor(lsA, 16);  lsA += __shfl_xor(lsA, 32);
  lsB += __shfl_xor(lsB, 16);  lsB += __shfl_xor(lsB, 32);
  if (g == 0) {
    lsumP[((z * NH + h) << 12) + qrowA] = lsA;
    lsumP[((z * NH + h) << 12) + qrowB] = lsB;
  }
  float* cpA = accP + z * (NN * 256) + (qrowA << 8) + (h << 5) + (g << 2);
  *(float4*)cpA        = make_float4(accA0.x, accA0.y, accA0.z, accA0.w);
  *(float4*)(cpA + 16) = make_float4(accA1.x, accA1.y, accA1.z, accA1.w);
  float* cpB = accP + z * (NN * 256) + (qrowB << 8) + (h << 5) + (g << 2);
  *(float4*)cpB        = make_float4(accB0.x, accB0.y, accB0.z, accB0.w);
  *(float4*)(cpB + 16) = make_float4(accB1.x, accB1.y, accB1.z, accB1.w);
}

// r8-validated combine+normalize+GEMM, 4 rows per block, 1024 blocks.
__device__ __forceinline__ void out_body(
    int bid, int tid, void* smem,
    const float* __restrict__ accP, const float* __restrict__ lsumP,
    const float* __restrict__ Wo, const float* __restrict__ bo,
    float* __restrict__ out, int S)
{
  float (*cn)[256] = (float(*)[256])smem;                       // 4 KB
  float (*sQ)[4][16] = (float(*)[4][16])((char*)smem + 4096);   // 1 KB
  const int n0 = bid << 2;

  {
    const int r = tid >> 6, u = tid & 63;
    const int n = n0 + r;
    float4 o = make_float4(0.f, 0.f, 0.f, 0.f);
    for (int s = 0; s < S; ++s) {
      const float4 v = *(const float4*)(accP + (size_t)s * (NN * 256) + (n << 8) + (u << 2));
      o.x += v.x; o.y += v.y; o.z += v.z; o.w += v.w;
    }
    const int hh = u >> 3;         // head of j-range (4 | 32, no straddle)
    float l = 0.f;
    for (int s = 0; s < S; ++s) l += lsumP[((s * NH + hh) << 12) + n];
    const float inv = 1.0f / l;
    *(float4*)&cn[r][u << 2] = make_float4(o.x * inv, o.y * inv, o.z * inv, o.w * inv);
  }
  __syncthreads();

  {
    const int r = tid >> 6, ks = (tid >> 4) & 3, c = tid & 15;
    const float* cr = &cn[r][ks << 6];
    const float* wp = Wo + (ks << 6) * 16 + c;
    float a = 0.f;
#pragma unroll
    for (int jj = 0; jj < 64; ++jj) {
      const int j2 = (jj + (ks << 4)) & 63;   // ks-rotation: 2-way LDS banks max
      a = fmaf(cr[j2], wp[j2 * 16], a);
    }
    sQ[r][ks][c] = a;
  }
  __syncthreads();

  if (tid < 64) {
    const int r = tid >> 4, c = tid & 15;
    float v = bo[c] + ((sQ[r][0][c] + sQ[r][1][c]) + (sQ[r][2][c] + sQ[r][3][c]));
    out[((n0 + r) << 4) + c] = v;
  }
}

// ---------------- fused cooperative kernel: proj | flash | out ----------------
__global__ __launch_bounds__(256, 4) void fused_kernel(
    const float* x, const float* y,
    const float* Wq, const float* bq, const float* Wk, const float* bk,
    const float* Wv, const float* bv, const float* Wo, const float* bo,
    u16* qs, u16* ks, u16* vT, float* accP, float* lsumP, float* out)
{
  extern __shared__ __align__(16) char smem[];
  cg::grid_group grid = cg::this_grid();
  const int bid = blockIdx.x;
  const int tid = threadIdx.x;

  if (bid < 384)
    proj_body(bid, tid, smem, x, y, Wq, bq, Wk, bk, Wv, bv, qs, ks, vT);
  grid.sync();
  flash_body(bid, tid, smem, qs, ks, vT, accP, lsumP);
  grid.sync();
  out_body(bid, tid, smem, accP, lsumP, Wo, bo, out, 4);
}

// ---------------- standalone fallback kernels (r7-exact path) ----------------
__global__ __launch_bounds__(256) void proj_kernel(
    const float* __restrict__ x, const float* __restrict__ y,
    const float* __restrict__ Wq, const float* __restrict__ bq,
    const float* __restrict__ Wk, const float* __restrict__ bk,
    const float* __restrict__ Wv, const float* __restrict__ bv,
    u16* __restrict__ qs, u16* __restrict__ ks, u16* __restrict__ vT)
{
  __shared__ u16 sv[256][33];
  proj_body(blockIdx.x, threadIdx.x, sv, x, y, Wq, bq, Wk, bk, Wv, bv, qs, ks, vT);
}

__global__ __launch_bounds__(256) void flash_kernel(
    const u16* __restrict__ qs, const u16* __restrict__ ksrc,
    const u16* __restrict__ vT, float* __restrict__ accP,
    float* __restrict__ lsumP)
{
  __shared__ u16 sbuf[128 * KST + 2 * VSZ];
  flash_body(blockIdx.x, threadIdx.x, sbuf, qs, ksrc, vT, accP, lsumP);
}

__global__ __launch_bounds__(256) void out_fused_kernel(
    const float* __restrict__ accP, const float* __restrict__ lsumP,
    const float* __restrict__ Wo, const float* __restrict__ bo,
    float* __restrict__ out, int S)
{
  __shared__ __align__(16) char sbuf[5120];
  out_body(blockIdx.x, threadIdx.x, sbuf, accP, lsumP, Wo, bo, out, S);
}

extern "C" void kernel_launch(void* const* d_in, const int* in_sizes, int n_in,
                              void* d_out, int out_size, void* d_ws, size_t ws_size,
                              hipStream_t stream) {
  const float* x  = (const float*)d_in[0];
  const float* y  = (const float*)d_in[1];
  const float* Wq = (const float*)d_in[2];
  const float* bq = (const float*)d_in[3];
  const float* Wk = (const float*)d_in[4];
  const float* bk = (const float*)d_in[5];
  const float* Wv = (const float*)d_in[6];
  const float* bv = (const float*)d_in[7];
  const float* Wo = (const float*)d_in[8];
  const float* bo = (const float*)d_in[9];
  float* out = (float*)d_out;

  u16* qs = (u16*)d_ws;                       // [8][4096][32] bf16  (2 MB)
  u16* ks = qs + (NH * NN * 32);              // [8][4096][32] bf16  (2 MB)
  u16* vT = ks + (NH * MM * 32);              // [8][32][4096] bf16  (2 MB, key-permuted)
  float* accP = (float*)(vT + (NH * MM * 32)); // [4][4096][256] f32 partials (16 MB)
  float* lsumP = accP + (size_t)4 * (NN * 256); // [4][8][4096] f32

  void* params[16] = {
    (void*)&x, (void*)&y, (void*)&Wq, (void*)&bq, (void*)&Wk, (void*)&bk,
    (void*)&Wv, (void*)&bv, (void*)&Wo, (void*)&bo,
    (void*)&qs, (void*)&ks, (void*)&vT, (void*)&accP, (void*)&lsumP, (void*)&out
  };
  hipError_t err = hipLaunchCooperativeKernel(
      reinterpret_cast<void*>(fused_kernel), dim3(1024), dim3(256),
      params, SMEM_BYTES, stream);
  if (err != hipSuccess) {
    // fallback: verified r7 4-kernel path
    hipLaunchKernelGGL(proj_kernel, dim3(384), dim3(256), 0, stream,
                       x, y, Wq, bq, Wk, bk, Wv, bv, qs, ks, vT);
    hipLaunchKernelGGL(flash_kernel, dim3(1024), dim3(256), 0, stream,
                       qs, ks, vT, accP, lsumP);
    hipLaunchKernelGGL(out_fused_kernel, dim3(1024), dim3(256), 0, stream,
                       accP, lsumP, Wo, bo, out, 4);
  }
}

// Round 14
// 63.483 us; speedup vs baseline: 5.4197x; 5.4197x over previous
//
#include <hip/hip_runtime.h>
#include <hip/hip_bf16.h>

typedef __attribute__((ext_vector_type(8))) short bf16x8;
typedef __attribute__((ext_vector_type(4))) float f32x4;
typedef unsigned short u16;
typedef unsigned int u32;

#define NH 8
#define NN 4096
#define MM 4096

__device__ __forceinline__ u16 f2bf(float f) {
  u32 b = __float_as_uint(f);
  b += 0x7FFFu + ((b >> 16) & 1u);   // RNE to bf16
  return (u16)(b >> 16);
}

// pack two positive floats to bf16 pair {lo:a, hi:b}, round-half-up
__device__ __forceinline__ u32 pack_rnu(float a, float b) {
  u32 ua = __float_as_uint(a) + 0x8000u;
  u32 ub = __float_as_uint(b) + 0x8000u;
#if __has_builtin(__builtin_amdgcn_perm)
  return __builtin_amdgcn_perm(ub, ua, 0x07060302u);  // {ua.b2,ua.b3,ub.b2,ub.b3}
#else
  return (ua >> 16) | (ub & 0xFFFF0000u);
#endif
}

#if __has_builtin(__builtin_amdgcn_exp2f)
__device__ __forceinline__ float exp2_fast(float x) { return __builtin_amdgcn_exp2f(x); }
#else
__device__ __forceinline__ float exp2_fast(float x) { return __expf(x * 0.69314718055994531f); }
#endif

// ---------------- fused projections: blocks 0..511 = q/k (2 thr/row), 512..639 = v ----
// v is written transposed AND key-permuted within each 32-key chunk:
//   position p (0..31) holds key k(p) = 16*((p>>2)&1) + 4*(p>>3) + (p&3)
// so flash's PV A-fragment (slot map k = 4g+(j&3)+16(j>>2)) is one b128 at 8g.
__global__ __launch_bounds__(256) void proj_kernel(
    const float* __restrict__ x, const float* __restrict__ y,
    const float* __restrict__ Wq, const float* __restrict__ bq,
    const float* __restrict__ Wk, const float* __restrict__ bk,
    const float* __restrict__ Wv, const float* __restrict__ bv,
    u16* __restrict__ qs, u16* __restrict__ ks, u16* __restrict__ vT)
{
  __shared__ u16 sv[256][33];
  const int bid = blockIdx.x;
  const int tid = threadIdx.x;
  if (bid < 512) {
    // ---- q/k path: 131072 threads, 2 per row (16 outputs each) ----
    int idx = bid * 256 + tid;
    int t = idx >> 16;                          // 0 = q (from x), 1 = k (from y)
    int i2 = idx & 65535;
    int h = i2 >> 13;
    int row = (i2 & 8191) >> 1;
    int half = i2 & 1;                          // output cols [16*half, 16*half+16)
    const float* src = (t ? y : x) + row * 16;
    const float* W = (t ? Wk : Wq) + (h << 9) + (half << 4);
    const float* b = (t ? bk : bq) + (h << 5) + (half << 4);
    // q scale = (1/sqrt(32)) * log2(e) so softmax is exp2(score)
    const float scale = t ? 1.0f : 0.25503635116465163f;
    float4 r4[4];
#pragma unroll
    for (int i = 0; i < 4; ++i) r4[i] = ((const float4*)src)[i];
    const float* r = (const float*)r4;
    u16* out = (t ? ks : qs) + (((h << 12) + row) << 5) + (half << 4);
#pragma unroll
    for (int j = 0; j < 16; ++j) {
      float a = b[j];
#pragma unroll
      for (int i = 0; i < 16; ++i) a = fmaf(r[i], W[i * 32 + j], a);
      out[j] = f2bf(a * scale);
    }
  } else {
    // ---- v path ----
    int vb = bid - 512;
    int h = vb >> 4;
    int kb = (vb & 15) << 8;           // 256 keys per block
    const float* src = y + (kb + tid) * 16;
    const float* W = Wv + (h << 9);
    const float* b = bv + (h << 5);
    float4 r4[4];
#pragma unroll
    for (int i = 0; i < 4; ++i) r4[i] = ((const float4*)src)[i];
    const float* r = (const float*)r4;
#pragma unroll
    for (int j = 0; j < 32; ++j) {
      float a = b[j];
#pragma unroll
      for (int i = 0; i < 16; ++i) a = fmaf(r[i], W[i * 32 + j], a);
      sv[tid][j] = f2bf(a);
    }
    __syncthreads();
    int dv = tid >> 3;
    int c = (tid & 7) << 5;            // 32-key chunk
    u16* dst = vT + (((h << 5) + dv) << 12) + kb + c;
#pragma unroll
    for (int q = 0; q < 4; ++q) {      // positions 8q..8q+7 <- keys {4q+r, 16+4q+r}
      uint4 w;
      w.x = (u32)sv[c + 4 * q + 0][dv]      | ((u32)sv[c + 4 * q + 1][dv] << 16);
      w.y = (u32)sv[c + 4 * q + 2][dv]      | ((u32)sv[c + 4 * q + 3][dv] << 16);
      w.z = (u32)sv[c + 16 + 4 * q + 0][dv] | ((u32)sv[c + 16 + 4 * q + 1][dv] << 16);
      w.w = (u32)sv[c + 16 + 4 * q + 2][dv] | ((u32)sv[c + 16 + 4 * q + 3][dv] << 16);
      *(uint4*)(dst + q * 8) = w;
    }
  }
}

// ---------------- flash attention (key-split partials): S^T = K Q^T, O^T = V^T P^T ----
// Round-7-EXACT: 2 q-tiles/wave, KVBLK=128 single-buffer (2 barriers/stage),
// aligned strides, register prefetch (T14), no-max exp2 softmax, pack_rnu,
// VALU lsum, grid dim3(32, NH, 4).
#define KST 40                  // K LDS row stride in u16 (80 B, 16B-aligned)
#define VST 72                  // V LDS row stride in u16 (144 B, 16B-aligned)
#define VSZ (32 * VST)          // one 64-key V sub-tile

__global__ __launch_bounds__(256) void flash_kernel(
    const u16* __restrict__ qs, const u16* __restrict__ ksrc,
    const u16* __restrict__ vT, float* __restrict__ accP,
    float* __restrict__ lsumP)
{
  __shared__ u16 sK[128 * KST];    // 128 keys x 32 dq  (10240 B)
  __shared__ u16 sVT[2 * VSZ];     // 2 sub x 32 dv x 64 keys (9216 B)
  const int h = blockIdx.y;
  const int qt = blockIdx.x;
  const int z = blockIdx.z;
  const int nIter = (MM / 128) / gridDim.z;        // stages of 128 keys
  const int kb0 = z * (MM / gridDim.z);            // first key of this split
  const int tid = threadIdx.x;
  const int wv = tid >> 6;
  const int lane = tid & 63;
  const int d = lane & 15;        // qrow-in-16 / A-row index / C col
  const int g = lane >> 4;        // lane group
  const int qrowA = (qt << 7) + (wv << 5) + d;     // wave owns rows [wv*32, wv*32+32)
  const int qrowB = qrowA + 16;

  union U4 { uint4 q; bf16x8 v; };
  // Q fragments, contiguous k-relabel: slot (g,j) -> k = 8g+j (same map on K side)
  U4 qfA, qfB;
  qfA.q = *(const uint4*)(qs + (((h << 12) + qrowA) << 5) + (g << 3));
  qfB.q = *(const uint4*)(qs + (((h << 12) + qrowB) << 5) + (g << 3));

  float lsA = 0.f, lsB = 0.f;
  f32x4 accA0 = {0.f, 0.f, 0.f, 0.f}, accA1 = {0.f, 0.f, 0.f, 0.f};
  f32x4 accB0 = {0.f, 0.f, 0.f, 0.f}, accB1 = {0.f, 0.f, 0.f, 0.f};
  const f32x4 zero = {0.f, 0.f, 0.f, 0.f};

  // staging addresses
  const u16* gK = ksrc + (h << 17) + (kb0 << 5) + ((tid >> 1) << 5) + ((tid & 1) << 4);
  const u16* gV = vT + (((h << 5) + (tid >> 3)) << 12) + kb0 + ((tid & 7) << 4);
  u16* wK = sK + (tid >> 1) * KST + ((tid & 1) << 4);
  u16* wV = sVT + ((tid & 7) >> 2) * VSZ + (tid >> 3) * VST + ((tid & 7) & 3) * 16;

  // prologue: stage this split's first 128 keys
  {
    uint4 a = *(const uint4*)gK, b = *(const uint4*)(gK + 8);
    uint4 c = *(const uint4*)gV, e = *(const uint4*)(gV + 8);
    *(uint4*)wK = a; *(uint4*)(wK + 8) = b;
    *(uint4*)wV = c; *(uint4*)(wV + 8) = e;
  }
  __syncthreads();

  auto compute = [&](const u16* kb, const u16* vb) {
    U4 kf0, kf1, kf2, kf3;          // K frags: keys 16t+d, k = 8g+j contiguous
    kf0.q = *(const uint4*)(kb + (0 * 16 + d) * KST + (g << 3));
    kf1.q = *(const uint4*)(kb + (1 * 16 + d) * KST + (g << 3));
    kf2.q = *(const uint4*)(kb + (2 * 16 + d) * KST + (g << 3));
    kf3.q = *(const uint4*)(kb + (3 * 16 + d) * KST + (g << 3));
    // V frags (vT key-permuted: group-g slot block at position 8g), serve both tiles
    U4 vf0, vf1, vf2, vf3;
    {
      const u16* vp = vb + d * VST;
      vf0.q = *(const uint4*)(vp + (g << 3));
      vf1.q = *(const uint4*)(vp + 32 + (g << 3));
      vp += 16 * VST;
      vf2.q = *(const uint4*)(vp + (g << 3));
      vf3.q = *(const uint4*)(vp + 32 + (g << 3));
    }
#define QTILE(QF, ACC0, ACC1, LS)                                              \
    {                                                                          \
      f32x4 s0, s1, s2, s3;                                                    \
      s0 = __builtin_amdgcn_mfma_f32_16x16x32_bf16(kf0.v, QF.v, zero, 0, 0, 0);\
      s1 = __builtin_amdgcn_mfma_f32_16x16x32_bf16(kf1.v, QF.v, zero, 0, 0, 0);\
      s2 = __builtin_amdgcn_mfma_f32_16x16x32_bf16(kf2.v, QF.v, zero, 0, 0, 0);\
      s3 = __builtin_amdgcn_mfma_f32_16x16x32_bf16(kf3.v, QF.v, zero, 0, 0, 0);\
      float e0 = exp2_fast(s0.x), e1 = exp2_fast(s0.y);                        \
      float e2 = exp2_fast(s0.z), e3 = exp2_fast(s0.w);                        \
      float e4 = exp2_fast(s1.x), e5 = exp2_fast(s1.y);                        \
      float e6 = exp2_fast(s1.z), e7 = exp2_fast(s1.w);                        \
      float e8 = exp2_fast(s2.x), e9 = exp2_fast(s2.y);                        \
      float e10 = exp2_fast(s2.z), e11 = exp2_fast(s2.w);                      \
      float e12 = exp2_fast(s3.x), e13 = exp2_fast(s3.y);                      \
      float e14 = exp2_fast(s3.z), e15 = exp2_fast(s3.w);                      \
      LS += (((e0 + e1) + (e2 + e3)) + ((e4 + e5) + (e6 + e7)))                \
          + (((e8 + e9) + (e10 + e11)) + ((e12 + e13) + (e14 + e15)));         \
      union { u32 w[4]; bf16x8 v; } pb0, pb1;                                  \
      pb0.w[0] = pack_rnu(e0, e1);   pb0.w[1] = pack_rnu(e2, e3);              \
      pb0.w[2] = pack_rnu(e4, e5);   pb0.w[3] = pack_rnu(e6, e7);              \
      pb1.w[0] = pack_rnu(e8, e9);   pb1.w[1] = pack_rnu(e10, e11);            \
      pb1.w[2] = pack_rnu(e12, e13); pb1.w[3] = pack_rnu(e14, e15);            \
      ACC0 = __builtin_amdgcn_mfma_f32_16x16x32_bf16(vf0.v, pb0.v, ACC0, 0, 0, 0); \
      ACC0 = __builtin_amdgcn_mfma_f32_16x16x32_bf16(vf1.v, pb1.v, ACC0, 0, 0, 0); \
      ACC1 = __builtin_amdgcn_mfma_f32_16x16x32_bf16(vf2.v, pb0.v, ACC1, 0, 0, 0); \
      ACC1 = __builtin_amdgcn_mfma_f32_16x16x32_bf16(vf3.v, pb1.v, ACC1, 0, 0, 0); \
    }
    QTILE(qfA, accA0, accA1, lsA)
    QTILE(qfB, accB0, accB1, lsB)
#undef QTILE
  };

#pragma unroll 1
  for (int it = 0; it < nIter; ++it) {
    uint4 a, b, c, e;
    if (it < nIter - 1) {            // prefetch next 128 keys into registers
      gK += 4096; gV += 128;
      a = *(const uint4*)gK; b = *(const uint4*)(gK + 8);
      c = *(const uint4*)gV; e = *(const uint4*)(gV + 8);
    }
    compute(sK, sVT);
    compute(sK + 64 * KST, sVT + VSZ);
    __syncthreads();               // all reads of current stage done
    if (it < nIter - 1) {
      *(uint4*)wK = a; *(uint4*)(wK + 8) = b;   // vmcnt drained under compute
      *(uint4*)wV = c; *(uint4*)(wV + 8) = e;
      __syncthreads();             // stage visible
    }
  }

  // cross-lane reduce of the denominators; store per qrow (g==0 lanes)
  lsA += __shfl_xor(lsA, 16);  lsA += __shfl_xor(lsA, 32);
  lsB += __shfl_xor(lsB, 16);  lsB += __shfl_xor(lsB, 32);
  if (g == 0) {
    lsumP[((z * NH + h) << 12) + qrowA] = lsA;
    lsumP[((z * NH + h) << 12) + qrowB] = lsB;
  }
  // unnormalized partial O
  float* cpA = accP + z * (NN * 256) + (qrowA << 8) + (h << 5) + (g << 2);
  *(float4*)cpA        = make_float4(accA0.x, accA0.y, accA0.z, accA0.w);
  *(float4*)(cpA + 16) = make_float4(accA1.x, accA1.y, accA1.z, accA1.w);
  float* cpB = accP + z * (NN * 256) + (qrowB << 8) + (h << 5) + (g << 2);
  *(float4*)cpB        = make_float4(accB0.x, accB0.y, accB0.z, accB0.w);
  *(float4*)(cpB + 16) = make_float4(accB1.x, accB1.y, accB1.z, accB1.w);
}

// ---------------- fused combine + output projection (1024 blocks, 4 rows each) ----
// out[n][c] = bo[c] + sum_j ((sum_s accP[s][n][j]) / (sum_s lsum[s][h(j)][n])) * Wo[j][c]
__global__ __launch_bounds__(256) void out_fused_kernel(
    const float* __restrict__ accP, const float* __restrict__ lsumP,
    const float* __restrict__ Wo, const float* __restrict__ bo,
    float* __restrict__ out, int S)
{
  __shared__ float cn[4][256];     // normalized concat rows (4 KB)
  __shared__ float sQ[4][4][16];   // per (row, kslice, col) partials
  const int tid = threadIdx.x;
  const int n0 = blockIdx.x << 2;

  // stage cn: thread (r = tid>>6, u = tid&63) handles j = 4u..4u+3 of row n0+r
  {
    const int r = tid >> 6, u = tid & 63;
    const int n = n0 + r;
    float4 o = make_float4(0.f, 0.f, 0.f, 0.f);
    for (int s = 0; s < S; ++s) {
      const float4 v = *(const float4*)(accP + (size_t)s * (NN * 256) + (n << 8) + (u << 2));
      o.x += v.x; o.y += v.y; o.z += v.z; o.w += v.w;
    }
    const int hh = u >> 3;         // head of j-range (4 | 32, no straddle)
    float l = 0.f;
    for (int s = 0; s < S; ++s) l += lsumP[((s * NH + hh) << 12) + n];
    const float inv = 1.0f / l;
    *(float4*)&cn[r][u << 2] = make_float4(o.x * inv, o.y * inv, o.z * inv, o.w * inv);
  }
  __syncthreads();

  // GEMM: thread (r = tid>>6, ks = (tid>>4)&3, c = tid&15), 64 j per thread
  {
    const int r = tid >> 6, ks = (tid >> 4) & 3, c = tid & 15;
    const float* cr = &cn[r][ks << 6];
    const float* wp = Wo + (ks << 6) * 16 + c;
    float a = 0.f;
#pragma unroll
    for (int jj = 0; jj < 64; ++jj) {
      const int j2 = (jj + (ks << 4)) & 63;   // ks-rotation: 2-way LDS banks max
      a = fmaf(cr[j2], wp[j2 * 16], a);
    }
    sQ[r][ks][c] = a;
  }
  __syncthreads();

  if (tid < 64) {
    const int r = tid >> 4, c = tid & 15;
    float v = bo[c] + ((sQ[r][0][c] + sQ[r][1][c]) + (sQ[r][2][c] + sQ[r][3][c]));
    out[((n0 + r) << 4) + c] = v;
  }
}

extern "C" void kernel_launch(void* const* d_in, const int* in_sizes, int n_in,
                              void* d_out, int out_size, void* d_ws, size_t ws_size,
                              hipStream_t stream) {
  const float* x  = (const float*)d_in[0];
  const float* y  = (const float*)d_in[1];
  const float* Wq = (const float*)d_in[2];
  const float* bq = (const float*)d_in[3];
  const float* Wk = (const float*)d_in[4];
  const float* bk = (const float*)d_in[5];
  const float* Wv = (const float*)d_in[6];
  const float* bv = (const float*)d_in[7];
  const float* Wo = (const float*)d_in[8];
  const float* bo = (const float*)d_in[9];
  float* out = (float*)d_out;

  u16* qs = (u16*)d_ws;                       // [8][4096][32] bf16  (2 MB)
  u16* ks = qs + (NH * NN * 32);              // [8][4096][32] bf16  (2 MB)
  u16* vT = ks + (NH * MM * 32);              // [8][32][4096] bf16  (2 MB, key-permuted)
  float* accP = (float*)(vT + (NH * MM * 32)); // [4][4096][256] f32 partials (16 MB)
  const int S = 4;                            // key-splits (ws: 6+16+0.5 MB)
  float* lsumP = accP + (size_t)S * (NN * 256); // [S][8][4096] f32

  hipLaunchKernelGGL(proj_kernel, dim3(640), dim3(256), 0, stream,
                     x, y, Wq, bq, Wk, bk, Wv, bv, qs, ks, vT);
  hipLaunchKernelGGL(flash_kernel, dim3(32, NH, S), dim3(256), 0, stream,
                     qs, ks, vT, accP, lsumP);
  hipLaunchKernelGGL(out_fused_kernel, dim3(1024), dim3(256), 0, stream,
                     accP, lsumP, Wo, bo, out, S);
}

// Round 15
// 62.020 us; speedup vs baseline: 5.5475x; 1.0236x over previous
//
#include <hip/hip_runtime.h>
#include <hip/hip_bf16.h>

typedef __attribute__((ext_vector_type(8))) short bf16x8;
typedef __attribute__((ext_vector_type(4))) float f32x4;
typedef unsigned short u16;
typedef unsigned int u32;

#define NH 8
#define NN 4096
#define MM 4096

__device__ __forceinline__ u16 f2bf(float f) {
  u32 b = __float_as_uint(f);
  b += 0x7FFFu + ((b >> 16) & 1u);   // RNE to bf16
  return (u16)(b >> 16);
}

// pack two positive floats to bf16 pair {lo:a, hi:b}, round-half-up
__device__ __forceinline__ u32 pack_rnu(float a, float b) {
  u32 ua = __float_as_uint(a) + 0x8000u;
  u32 ub = __float_as_uint(b) + 0x8000u;
#if __has_builtin(__builtin_amdgcn_perm)
  return __builtin_amdgcn_perm(ub, ua, 0x07060302u);  // {ua.b2,ua.b3,ub.b2,ub.b3}
#else
  return (ua >> 16) | (ub & 0xFFFF0000u);
#endif
}

#if __has_builtin(__builtin_amdgcn_exp2f)
__device__ __forceinline__ float exp2_fast(float x) { return __builtin_amdgcn_exp2f(x); }
#else
__device__ __forceinline__ float exp2_fast(float x) { return __expf(x * 0.69314718055994531f); }
#endif

// ---------------- fused projections: blocks 0..255 = q/k, 256..383 = v ----------------
// v is written transposed AND key-permuted within each 32-key chunk:
//   position p (0..31) holds key k(p) = 16*((p>>2)&1) + 4*(p>>3) + (p&3)
// so flash's PV A-fragment (slot map k = 4g+(j&3)+16(j>>2)) is one b128 at 8g.
__global__ __launch_bounds__(256) void proj_kernel(
    const float* __restrict__ x, const float* __restrict__ y,
    const float* __restrict__ Wq, const float* __restrict__ bq,
    const float* __restrict__ Wk, const float* __restrict__ bk,
    const float* __restrict__ Wv, const float* __restrict__ bv,
    u16* __restrict__ qs, u16* __restrict__ ks, u16* __restrict__ vT)
{
  __shared__ u16 sv[256][33];
  const int bid = blockIdx.x;
  const int tid = threadIdx.x;
  if (bid < 256) {
    // ---- q/k path ----
    int idx = bid * 256 + tid;                  // 65536 total
    int t = idx >> 15;                          // 0 = q (from x), 1 = k (from y)
    int h = (idx >> 12) & 7;
    int row = idx & 4095;
    const float* src = (t ? y : x) + row * 16;
    const float* W = (t ? Wk : Wq) + (h << 9);
    const float* b = (t ? bk : bq) + (h << 5);
    // q scale = (1/sqrt(32)) * log2(e) so softmax is exp2(score)
    const float scale = t ? 1.0f : 0.25503635116465163f;
    float4 r4[4];
#pragma unroll
    for (int i = 0; i < 4; ++i) r4[i] = ((const float4*)src)[i];
    const float* r = (const float*)r4;
    u16* out = (t ? ks : qs) + (idx & 32767) * 32;      // (h*4096+row)*32
#pragma unroll
    for (int j = 0; j < 32; ++j) {
      float a = b[j];
#pragma unroll
      for (int i = 0; i < 16; ++i) a = fmaf(r[i], W[i * 32 + j], a);
      out[j] = f2bf(a * scale);
    }
  } else {
    // ---- v path ----
    int vb = bid - 256;
    int h = vb >> 4;
    int kb = (vb & 15) << 8;           // 256 keys per block
    const float* src = y + (kb + tid) * 16;
    const float* W = Wv + (h << 9);
    const float* b = bv + (h << 5);
    float4 r4[4];
#pragma unroll
    for (int i = 0; i < 4; ++i) r4[i] = ((const float4*)src)[i];
    const float* r = (const float*)r4;
#pragma unroll
    for (int j = 0; j < 32; ++j) {
      float a = b[j];
#pragma unroll
      for (int i = 0; i < 16; ++i) a = fmaf(r[i], W[i * 32 + j], a);
      sv[tid][j] = f2bf(a);
    }
    __syncthreads();
    int dv = tid >> 3;
    int c = (tid & 7) << 5;            // 32-key chunk
    u16* dst = vT + (((h << 5) + dv) << 12) + kb + c;
#pragma unroll
    for (int q = 0; q < 4; ++q) {      // positions 8q..8q+7 <- keys {4q+r, 16+4q+r}
      uint4 w;
      w.x = (u32)sv[c + 4 * q + 0][dv]      | ((u32)sv[c + 4 * q + 1][dv] << 16);
      w.y = (u32)sv[c + 4 * q + 2][dv]      | ((u32)sv[c + 4 * q + 3][dv] << 16);
      w.z = (u32)sv[c + 16 + 4 * q + 0][dv] | ((u32)sv[c + 16 + 4 * q + 1][dv] << 16);
      w.w = (u32)sv[c + 16 + 4 * q + 2][dv] | ((u32)sv[c + 16 + 4 * q + 3][dv] << 16);
      *(uint4*)(dst + q * 8) = w;
    }
  }
}

// ---------------- flash attention (key-split partials): S^T = K Q^T, O^T = V^T P^T ----
// Round-4/5 verified inner structure; each wave owns 32 q-rows (two Q
// fragments) so each K/V b128 LDS read serves 2x the MFMA/softmax work.
// Block covers 128 q-rows; grid (NN/128, NH, S).
#define KST 40                  // K LDS row stride in u16 (80 B, 16B-aligned)
#define VST 72                  // V LDS row stride in u16 (144 B, 16B-aligned)
#define VSZ (32 * VST)          // one 64-key V sub-tile

__global__ __launch_bounds__(256) void flash_kernel(
    const u16* __restrict__ qs, const u16* __restrict__ ksrc,
    const u16* __restrict__ vT, float* __restrict__ accP,
    float* __restrict__ lsumP)
{
  __shared__ u16 sK[128 * KST];    // 128 keys x 32 dq  (10240 B)
  __shared__ u16 sVT[2 * VSZ];     // 2 sub x 32 dv x 64 keys (9216 B)
  const int h = blockIdx.y;
  const int qt = blockIdx.x;
  const int z = blockIdx.z;
  const int nIter = (MM / 128) / gridDim.z;        // stages of 128 keys
  const int kb0 = z * (MM / gridDim.z);            // first key of this split
  const int tid = threadIdx.x;
  const int wv = tid >> 6;
  const int lane = tid & 63;
  const int d = lane & 15;        // qrow-in-16 / A-row index / C col
  const int g = lane >> 4;        // lane group
  const int qrowA = (qt << 7) + (wv << 5) + d;     // wave owns rows [wv*32, wv*32+32)
  const int qrowB = qrowA + 16;

  union U4 { uint4 q; bf16x8 v; };
  // Q fragments, contiguous k-relabel: slot (g,j) -> k = 8g+j (same map on K side)
  U4 qfA, qfB;
  qfA.q = *(const uint4*)(qs + (((h << 12) + qrowA) << 5) + (g << 3));
  qfB.q = *(const uint4*)(qs + (((h << 12) + qrowB) << 5) + (g << 3));

  float lsA = 0.f, lsB = 0.f;
  f32x4 accA0 = {0.f, 0.f, 0.f, 0.f}, accA1 = {0.f, 0.f, 0.f, 0.f};
  f32x4 accB0 = {0.f, 0.f, 0.f, 0.f}, accB1 = {0.f, 0.f, 0.f, 0.f};
  const f32x4 zero = {0.f, 0.f, 0.f, 0.f};

  // staging addresses
  const u16* gK = ksrc + (h << 17) + (kb0 << 5) + ((tid >> 1) << 5) + ((tid & 1) << 4);
  const u16* gV = vT + (((h << 5) + (tid >> 3)) << 12) + kb0 + ((tid & 7) << 4);
  u16* wK = sK + (tid >> 1) * KST + ((tid & 1) << 4);
  u16* wV = sVT + ((tid & 7) >> 2) * VSZ + (tid >> 3) * VST + ((tid & 7) & 3) * 16;

  // prologue: stage this split's first 128 keys
  {
    uint4 a = *(const uint4*)gK, b = *(const uint4*)(gK + 8);
    uint4 c = *(const uint4*)gV, e = *(const uint4*)(gV + 8);
    *(uint4*)wK = a; *(uint4*)(wK + 8) = b;
    *(uint4*)wV = c; *(uint4*)(wV + 8) = e;
  }
  __syncthreads();

  auto compute = [&](const u16* kb, const u16* vb) {
    U4 kf0, kf1, kf2, kf3;          // K frags: keys 16t+d, k = 8g+j contiguous
    kf0.q = *(const uint4*)(kb + (0 * 16 + d) * KST + (g << 3));
    kf1.q = *(const uint4*)(kb + (1 * 16 + d) * KST + (g << 3));
    kf2.q = *(const uint4*)(kb + (2 * 16 + d) * KST + (g << 3));
    kf3.q = *(const uint4*)(kb + (3 * 16 + d) * KST + (g << 3));
    // V frags (vT key-permuted: group-g slot block at position 8g), serve both halves
    U4 vf0, vf1, vf2, vf3;
    {
      const u16* vp = vb + d * VST;
      vf0.q = *(const uint4*)(vp + (g << 3));
      vf1.q = *(const uint4*)(vp + 32 + (g << 3));
      vp += 16 * VST;
      vf2.q = *(const uint4*)(vp + (g << 3));
      vf3.q = *(const uint4*)(vp + 32 + (g << 3));
    }
#define QTILE(QF, ACC0, ACC1, LS)                                              \
    {                                                                          \
      f32x4 s0, s1, s2, s3;                                                    \
      s0 = __builtin_amdgcn_mfma_f32_16x16x32_bf16(kf0.v, QF.v, zero, 0, 0, 0);\
      s1 = __builtin_amdgcn_mfma_f32_16x16x32_bf16(kf1.v, QF.v, zero, 0, 0, 0);\
      s2 = __builtin_amdgcn_mfma_f32_16x16x32_bf16(kf2.v, QF.v, zero, 0, 0, 0);\
      s3 = __builtin_amdgcn_mfma_f32_16x16x32_bf16(kf3.v, QF.v, zero, 0, 0, 0);\
      float e0 = exp2_fast(s0.x), e1 = exp2_fast(s0.y);                        \
      float e2 = exp2_fast(s0.z), e3 = exp2_fast(s0.w);                        \
      float e4 = exp2_fast(s1.x), e5 = exp2_fast(s1.y);                        \
      float e6 = exp2_fast(s1.z), e7 = exp2_fast(s1.w);                        \
      float e8 = exp2_fast(s2.x), e9 = exp2_fast(s2.y);                        \
      float e10 = exp2_fast(s2.z), e11 = exp2_fast(s2.w);                      \
      float e12 = exp2_fast(s3.x), e13 = exp2_fast(s3.y);                      \
      float e14 = exp2_fast(s3.z), e15 = exp2_fast(s3.w);                      \
      LS += (((e0 + e1) + (e2 + e3)) + ((e4 + e5) + (e6 + e7)))                \
          + (((e8 + e9) + (e10 + e11)) + ((e12 + e13) + (e14 + e15)));         \
      union { u32 w[4]; bf16x8 v; } pb0, pb1;                                  \
      pb0.w[0] = pack_rnu(e0, e1);   pb0.w[1] = pack_rnu(e2, e3);              \
      pb0.w[2] = pack_rnu(e4, e5);   pb0.w[3] = pack_rnu(e6, e7);              \
      pb1.w[0] = pack_rnu(e8, e9);   pb1.w[1] = pack_rnu(e10, e11);            \
      pb1.w[2] = pack_rnu(e12, e13); pb1.w[3] = pack_rnu(e14, e15);            \
      ACC0 = __builtin_amdgcn_mfma_f32_16x16x32_bf16(vf0.v, pb0.v, ACC0, 0, 0, 0); \
      ACC0 = __builtin_amdgcn_mfma_f32_16x16x32_bf16(vf1.v, pb1.v, ACC0, 0, 0, 0); \
      ACC1 = __builtin_amdgcn_mfma_f32_16x16x32_bf16(vf2.v, pb0.v, ACC1, 0, 0, 0); \
      ACC1 = __builtin_amdgcn_mfma_f32_16x16x32_bf16(vf3.v, pb1.v, ACC1, 0, 0, 0); \
    }
    QTILE(qfA, accA0, accA1, lsA)
    QTILE(qfB, accB0, accB1, lsB)
#undef QTILE
  };

#pragma unroll 1
  for (int it = 0; it < nIter; ++it) {
    uint4 a, b, c, e;
    if (it < nIter - 1) {            // prefetch next 128 keys into registers
      gK += 4096; gV += 128;
      a = *(const uint4*)gK; b = *(const uint4*)(gK + 8);
      c = *(const uint4*)gV; e = *(const uint4*)(gV + 8);
    }
    compute(sK, sVT);
    compute(sK + 64 * KST, sVT + VSZ);
    __syncthreads();               // all reads of current stage done
    if (it < nIter - 1) {
      *(uint4*)wK = a; *(uint4*)(wK + 8) = b;   // vmcnt drained under compute
      *(uint4*)wV = c; *(uint4*)(wV + 8) = e;
      __syncthreads();             // stage visible
    }
  }

  // cross-lane reduce of this split's denominators; store per qrow (g==0 lanes)
  lsA += __shfl_xor(lsA, 16);
  lsA += __shfl_xor(lsA, 32);
  lsB += __shfl_xor(lsB, 16);
  lsB += __shfl_xor(lsB, 32);
  if (g == 0) {
    lsumP[((z * NH + h) << 12) + qrowA] = lsA;
    lsumP[((z * NH + h) << 12) + qrowB] = lsB;
  }
  // unnormalized partial O
  float* cpA = accP + z * (NN * 256) + (qrowA << 8) + (h << 5) + (g << 2);
  *(float4*)cpA        = make_float4(accA0.x, accA0.y, accA0.z, accA0.w);
  *(float4*)(cpA + 16) = make_float4(accA1.x, accA1.y, accA1.z, accA1.w);
  float* cpB = accP + z * (NN * 256) + (qrowB << 8) + (h << 5) + (g << 2);
  *(float4*)cpB        = make_float4(accB0.x, accB0.y, accB0.z, accB0.w);
  *(float4*)(cpB + 16) = make_float4(accB1.x, accB1.y, accB1.z, accB1.w);
}

// ---------------- combine: concat = (sum_s accP) / (sum_s lsum) ----------------
__global__ __launch_bounds__(256) void combine_kernel(
    const float* __restrict__ accP, const float* __restrict__ lsumP,
    float* __restrict__ concat, int S)
{
  int idx = blockIdx.x * 256 + threadIdx.x;  // over 4096*256
  int n = idx >> 8;
  int h = (idx & 255) >> 5;
  float o = 0.f, l = 0.f;
  for (int s = 0; s < S; ++s) {
    o += accP[s * (NN * 256) + idx];
    l += lsumP[((s * NH + h) << 12) + n];
  }
  concat[idx] = o / l;
}

// ---------------- output projection: out = concat @ Wo + bo ----------------
__global__ __launch_bounds__(256) void out_gemm_kernel(
    const float* __restrict__ concat, const float* __restrict__ Wo,
    const float* __restrict__ bo, float* __restrict__ out)
{
  __shared__ float sWo[4096];
  int tid = threadIdx.x;
  for (int i = tid; i < 4096; i += 256) sWo[i] = Wo[i];
  __syncthreads();
  int idx = blockIdx.x * 256 + tid;
  int n = idx >> 4;
  int c = idx & 15;
  const float4* crow = (const float4*)(concat + (n << 8));
  float a = bo[c];
#pragma unroll 4
  for (int i4 = 0; i4 < 64; ++i4) {
    float4 cv = crow[i4];
    a = fmaf(cv.x, sWo[(i4 * 4 + 0) * 16 + c], a);
    a = fmaf(cv.y, sWo[(i4 * 4 + 1) * 16 + c], a);
    a = fmaf(cv.z, sWo[(i4 * 4 + 2) * 16 + c], a);
    a = fmaf(cv.w, sWo[(i4 * 4 + 3) * 16 + c], a);
  }
  out[idx] = a;
}

extern "C" void kernel_launch(void* const* d_in, const int* in_sizes, int n_in,
                              void* d_out, int out_size, void* d_ws, size_t ws_size,
                              hipStream_t stream) {
  const float* x  = (const float*)d_in[0];
  const float* y  = (const float*)d_in[1];
  const float* Wq = (const float*)d_in[2];
  const float* bq = (const float*)d_in[3];
  const float* Wk = (const float*)d_in[4];
  const float* bk = (const float*)d_in[5];
  const float* Wv = (const float*)d_in[6];
  const float* bv = (const float*)d_in[7];
  const float* Wo = (const float*)d_in[8];
  const float* bo = (const float*)d_in[9];
  float* out = (float*)d_out;

  u16* qs = (u16*)d_ws;                       // [8][4096][32] bf16  (2 MB)
  u16* ks = qs + (NH * NN * 32);              // [8][4096][32] bf16  (2 MB)
  u16* vT = ks + (NH * MM * 32);              // [8][32][4096] bf16  (2 MB, key-permuted)
  float* concat = (float*)(vT + (NH * MM * 32)); // [4096][256] f32
  float* accP = concat;                       // partial O: S regions of 4 MB (accP[0]==concat)
  // key-split by available scratch: S=4 needs 6 + 16 + 0.5 MB
  const int S = (ws_size >= (size_t)(6 + 16) * 1024 * 1024 + 512 * 1024) ? 4 : 1;
  float* lsumP = accP + (size_t)S * (NN * 256); // [S][8][4096] f32

  hipLaunchKernelGGL(proj_kernel, dim3(384), dim3(256), 0, stream,
                     x, y, Wq, bq, Wk, bk, Wv, bv, qs, ks, vT);
  hipLaunchKernelGGL(flash_kernel, dim3(32, NH, S), dim3(256), 0, stream,
                     qs, ks, vT, accP, lsumP);
  hipLaunchKernelGGL(combine_kernel, dim3(4096), dim3(256), 0, stream,
                     accP, lsumP, concat, S);
  hipLaunchKernelGGL(out_gemm_kernel, dim3(256), dim3(256), 0, stream, concat, Wo, bo, out);
}